// Round 1
// baseline (318.624 us; speedup 1.0000x reference)
//
#include <hip/hip_runtime.h>

#define DIMC 256
#define RTOT 1024
#define NE 64
#define NSLOT 1024
#define TILE 16

// ---------------- bucket slots by expert ----------------
__global__ __launch_bounds__(1024) void bucket_kernel(
    const int* __restrict__ idx, int* __restrict__ count,
    int* __restrict__ start, int* __restrict__ list) {
  __shared__ int cnt[NE];
  __shared__ int offs[NE];
  __shared__ int cur[NE];
  int t = threadIdx.x;
  if (t < NE) cnt[t] = 0;
  __syncthreads();
  int e = idx[t] & (NE - 1);
  atomicAdd(&cnt[e], 1);
  __syncthreads();
  if (t == 0) {
    int acc = 0;
    for (int i = 0; i < NE; ++i) { offs[i] = acc; cur[i] = acc; acc += cnt[i]; }
  }
  __syncthreads();
  if (t < NE) { count[t] = cnt[t]; start[t] = offs[t]; }
  int pos = atomicAdd(&cur[e], 1);
  list[pos] = t;
}

// ---------------- fused 2-layer expert MLP ----------------
// grid: (4 r-chunks, 64 experts), block: 256 threads.
// Each block streams a disjoint 256-column chunk of w1[e] and the matching
// 256-row chunk of w2[e] exactly once from HBM.
__global__ __launch_bounds__(256) void mlp_kernel(
    const float* __restrict__ slots, const float* __restrict__ w1,
    const float* __restrict__ b1, const float* __restrict__ w2,
    const float* __restrict__ b2, const int* __restrict__ count,
    const int* __restrict__ start, const int* __restrict__ list,
    float* __restrict__ out) {
  const int rc = blockIdx.x;   // 0..3
  const int e  = blockIdx.y;   // 0..63
  const int n = count[e];
  if (n == 0) return;
  const int t = threadIdx.x;
  const int rbase = rc * 256;

  __shared__ float xh[TILE][DIMC];  // holds x tile, then reused for h tile
  __shared__ int sid[TILE];

  const float* p1 = w1 + (size_t)e * DIMC * RTOT + rbase + t;       // stride RTOT per d
  const float* p2 = w2 + ((size_t)e * RTOT + rbase) * DIMC + t;     // stride DIMC per r
  const float b1v = b1[e * RTOT + rbase + t];
  const float b2v = (rc == 0) ? b2[e * DIMC + t] : 0.0f;
  const int st = start[e];

  for (int s0 = 0; s0 < n; s0 += TILE) {
    int m = n - s0; if (m > TILE) m = TILE;

    __syncthreads();  // previous tile fully consumed before overwriting xh/sid
    if (t < TILE) {
      int si = (t < m) ? t : (m - 1);  // pad with a valid slot id
      sid[t] = list[st + s0 + si];
    }
    __syncthreads();

    // load x tile (TILE slots x 256 floats) via float4, coalesced rows
    for (int i4 = t; i4 < TILE * (DIMC / 4); i4 += 256) {
      int si = i4 >> 6;          // DIMC/4 = 64
      int d4 = i4 & 63;
      float4 v = ((const float4*)slots)[(size_t)sid[si] * (DIMC / 4) + d4];
      *(float4*)&xh[si][d4 * 4] = v;
    }
    __syncthreads();

    // ---- layer 1: h[s][rbase+t] = b1 + sum_d x[s][d] * w1[e][d][rbase+t]
    float acc[TILE];
#pragma unroll
    for (int s = 0; s < TILE; ++s) acc[s] = b1v;

#pragma unroll 2
    for (int d = 0; d < DIMC; d += 4) {
      float wa = p1[(size_t)(d + 0) * RTOT];
      float wb = p1[(size_t)(d + 1) * RTOT];
      float wc = p1[(size_t)(d + 2) * RTOT];
      float wd = p1[(size_t)(d + 3) * RTOT];
#pragma unroll
      for (int s = 0; s < TILE; ++s) {
        float4 x = *(const float4*)&xh[s][d];
        acc[s] = fmaf(x.x, wa, acc[s]);
        acc[s] = fmaf(x.y, wb, acc[s]);
        acc[s] = fmaf(x.z, wc, acc[s]);
        acc[s] = fmaf(x.w, wd, acc[s]);
      }
    }
    __syncthreads();

    // relu, park h tile in LDS (column writes: 2-way bank alias = free)
#pragma unroll
    for (int s = 0; s < TILE; ++s) xh[s][t] = fmaxf(acc[s], 0.0f);
    __syncthreads();

    // ---- layer 2 partial: out[s][t] += sum_{r in chunk} h[s][r] * w2[e][r][t]
    float o[TILE];
#pragma unroll
    for (int s = 0; s < TILE; ++s) o[s] = b2v;

#pragma unroll 2
    for (int r = 0; r < 256; r += 4) {
      float wa = p2[(size_t)(r + 0) * DIMC];
      float wb = p2[(size_t)(r + 1) * DIMC];
      float wc = p2[(size_t)(r + 2) * DIMC];
      float wd = p2[(size_t)(r + 3) * DIMC];
#pragma unroll
      for (int s = 0; s < TILE; ++s) {
        float4 h = *(const float4*)&xh[s][r];
        o[s] = fmaf(h.x, wa, o[s]);
        o[s] = fmaf(h.y, wb, o[s]);
        o[s] = fmaf(h.z, wc, o[s]);
        o[s] = fmaf(h.w, wd, o[s]);
      }
    }

    for (int s = 0; s < m; ++s) {
      atomicAdd(&out[(size_t)sid[s] * DIMC + t], o[s]);
    }
  }
}

extern "C" void kernel_launch(void* const* d_in, const int* in_sizes, int n_in,
                              void* d_out, int out_size, void* d_ws, size_t ws_size,
                              hipStream_t stream) {
  const float* slots   = (const float*)d_in[0];
  const float* w1      = (const float*)d_in[1];
  const float* b1      = (const float*)d_in[2];
  const float* w2      = (const float*)d_in[3];
  const float* b2      = (const float*)d_in[4];
  const int*   indices = (const int*)d_in[5];
  float* out = (float*)d_out;

  int* ws    = (int*)d_ws;
  int* count = ws;         // 64
  int* start = ws + 64;    // 64
  int* list  = ws + 128;   // 1024

  hipMemsetAsync(d_out, 0, (size_t)out_size * sizeof(float), stream);
  bucket_kernel<<<1, NSLOT, 0, stream>>>(indices, count, start, list);
  mlp_kernel<<<dim3(4, NE), 256, 0, stream>>>(slots, w1, b1, w2, b2,
                                              count, start, list, out);
}

// Round 2
// 230.123 us; speedup vs baseline: 1.3846x; 1.3846x over previous
//
#include <hip/hip_runtime.h>

#define DIMC 256
#define RTOT 1024
#define NE 64
#define NSLOT 1024
#define RC 256     // r-columns handled per block (grid.x = RTOT/RC = 4)
#define TILE 32    // slots per tile (covers max multinomial count in one pass)
#define SG 8       // slots per slot-group (4 groups = 4 waves)

// ---------------- bucket slots by expert ----------------
__global__ __launch_bounds__(1024) void bucket_kernel(
    const int* __restrict__ idx, int* __restrict__ count,
    int* __restrict__ start, int* __restrict__ list) {
  __shared__ int cnt[NE];
  __shared__ int offs[NE];
  __shared__ int cur[NE];
  int t = threadIdx.x;
  if (t < NE) cnt[t] = 0;
  __syncthreads();
  int e = idx[t] & (NE - 1);
  atomicAdd(&cnt[e], 1);
  __syncthreads();
  if (t == 0) {
    int acc = 0;
    for (int i = 0; i < NE; ++i) { offs[i] = acc; cur[i] = acc; acc += cnt[i]; }
  }
  __syncthreads();
  if (t < NE) { count[t] = cnt[t]; start[t] = offs[t]; }
  int pos = atomicAdd(&cur[e], 1);
  list[pos] = t;
}

static __device__ __forceinline__ float4 f4ma(float a, float4 w, float4 c) {
  c.x = fmaf(a, w.x, c.x);
  c.y = fmaf(a, w.y, c.y);
  c.z = fmaf(a, w.z, c.z);
  c.w = fmaf(a, w.w, c.w);
  return c;
}

// ---------------- fused 2-layer expert MLP ----------------
// grid: (4 r-chunks, 64 experts), block: 256 threads = 4 waves.
// Lane group g4 = t&63 owns 4 consecutive r (L1) / 4 consecutive d (L2);
// wave group sg = t>>6 owns 8 slots. The 4 waves duplicate-read the same
// weight stream (dedup'd by L1/L2); HBM sees each weight byte once.
__global__ __launch_bounds__(256) void mlp_kernel(
    const float* __restrict__ slots, const float* __restrict__ w1,
    const float* __restrict__ b1, const float* __restrict__ w2,
    const float* __restrict__ b2, const int* __restrict__ count,
    const int* __restrict__ start, const int* __restrict__ list,
    float* __restrict__ out) {
  const int rc = blockIdx.x;   // 0..3
  const int e  = blockIdx.y;   // 0..63
  const int n = count[e];
  if (n == 0) return;
  const int t  = threadIdx.x;
  const int g4 = t & 63;       // 64 groups of 4 columns
  const int sg = t >> 6;       // slot group 0..3
  const int rbase = rc * RC;

  __shared__ float xs[TILE][DIMC];  // x tile during L1, h tile during L2
  __shared__ int sid[TILE];

  const float* pw1 = w1 + (size_t)e * DIMC * RTOT + rbase + g4 * 4;  // stride RTOT per d
  const float* pw2 = w2 + ((size_t)e * RTOT + rbase) * DIMC + g4 * 4; // stride DIMC per r

  float4 b1v = *(const float4*)&b1[e * RTOT + rbase + g4 * 4];
  float4 b2v = (rc == 0) ? *(const float4*)&b2[e * DIMC + g4 * 4]
                         : make_float4(0.f, 0.f, 0.f, 0.f);
  const int st = start[e];

  for (int s0 = 0; s0 < n; s0 += TILE) {
    const int m = (n - s0 < TILE) ? (n - s0) : TILE;

    __syncthreads();  // prior tile fully consumed before overwriting sid/xs
    if (t < TILE) sid[t] = list[st + s0 + ((t < m) ? t : (m - 1))];
    __syncthreads();

    // load x tile (TILE x 256 floats) via float4, coalesced
    for (int i = t; i < TILE * (DIMC / 4); i += 256) {
      int s = i >> 6, d4 = i & 63;
      *(float4*)&xs[s][d4 * 4] =
          ((const float4*)slots)[(size_t)sid[s] * (DIMC / 4) + d4];
    }
    __syncthreads();

    // ---- layer 1: acc[s][0..3] = b1 + sum_d x[s][d] * w1[d][r4..r4+3]
    float4 acc[SG];
#pragma unroll
    for (int s = 0; s < SG; ++s) acc[s] = b1v;

#pragma unroll 4
    for (int d = 0; d < DIMC; d += 4) {
      float4 wA = *(const float4*)(pw1 + (size_t)(d + 0) * RTOT);
      float4 wB = *(const float4*)(pw1 + (size_t)(d + 1) * RTOT);
      float4 wC = *(const float4*)(pw1 + (size_t)(d + 2) * RTOT);
      float4 wD = *(const float4*)(pw1 + (size_t)(d + 3) * RTOT);
#pragma unroll
      for (int s = 0; s < SG; ++s) {
        float4 xv = *(const float4*)&xs[sg * SG + s][d];  // LDS broadcast
        acc[s] = f4ma(xv.x, wA, acc[s]);
        acc[s] = f4ma(xv.y, wB, acc[s]);
        acc[s] = f4ma(xv.z, wC, acc[s]);
        acc[s] = f4ma(xv.w, wD, acc[s]);
      }
    }
    __syncthreads();  // all x reads done; reuse xs for h

    // relu -> h tile
#pragma unroll
    for (int s = 0; s < SG; ++s) {
      float4 h;
      h.x = fmaxf(acc[s].x, 0.f);
      h.y = fmaxf(acc[s].y, 0.f);
      h.z = fmaxf(acc[s].z, 0.f);
      h.w = fmaxf(acc[s].w, 0.f);
      *(float4*)&xs[sg * SG + s][g4 * 4] = h;
    }
    __syncthreads();

    // ---- layer 2 partial: o[s][0..3] = b2 + sum_{r in chunk} h[s][r] * w2[r][d4..d4+3]
    float4 o[SG];
#pragma unroll
    for (int s = 0; s < SG; ++s) o[s] = b2v;

#pragma unroll 4
    for (int r = 0; r < RC; r += 4) {
      float4 wA = *(const float4*)(pw2 + (size_t)(r + 0) * DIMC);
      float4 wB = *(const float4*)(pw2 + (size_t)(r + 1) * DIMC);
      float4 wC = *(const float4*)(pw2 + (size_t)(r + 2) * DIMC);
      float4 wD = *(const float4*)(pw2 + (size_t)(r + 3) * DIMC);
#pragma unroll
      for (int s = 0; s < SG; ++s) {
        float4 hv = *(const float4*)&xs[sg * SG + s][r];  // LDS broadcast
        o[s] = f4ma(hv.x, wA, o[s]);
        o[s] = f4ma(hv.y, wB, o[s]);
        o[s] = f4ma(hv.z, wC, o[s]);
        o[s] = f4ma(hv.w, wD, o[s]);
      }
    }

    for (int s = 0; s < SG; ++s) {
      int ss = sg * SG + s;
      if (ss < m) {
        float* po = &out[(size_t)sid[ss] * DIMC + g4 * 4];
        atomicAdd(po + 0, o[s].x);
        atomicAdd(po + 1, o[s].y);
        atomicAdd(po + 2, o[s].z);
        atomicAdd(po + 3, o[s].w);
      }
    }
  }
}

extern "C" void kernel_launch(void* const* d_in, const int* in_sizes, int n_in,
                              void* d_out, int out_size, void* d_ws, size_t ws_size,
                              hipStream_t stream) {
  const float* slots   = (const float*)d_in[0];
  const float* w1      = (const float*)d_in[1];
  const float* b1      = (const float*)d_in[2];
  const float* w2      = (const float*)d_in[3];
  const float* b2      = (const float*)d_in[4];
  const int*   indices = (const int*)d_in[5];
  float* out = (float*)d_out;

  int* ws    = (int*)d_ws;
  int* count = ws;         // 64
  int* start = ws + 64;    // 64
  int* list  = ws + 128;   // 1024

  hipMemsetAsync(d_out, 0, (size_t)out_size * sizeof(float), stream);
  bucket_kernel<<<1, NSLOT, 0, stream>>>(indices, count, start, list);
  mlp_kernel<<<dim3(4, NE), 256, 0, stream>>>(slots, w1, b1, w2, b2,
                                              count, start, list, out);
}